// Round 13
// baseline (35952.371 us; speedup 1.0000x reference)
//
#include <hip/hip_runtime.h>
#include <hip/hip_cooperative_groups.h>
#include <math.h>

namespace cg = cooperative_groups;

// Problem constants (from reference)
#define Bsz   32
#define Lmem  512
#define Tsteps 400
#define EMBD  512
#define PRE   256
#define ENCD  512
#define ARNN  1024
#define DRNN  1024
#define NSYM  256
// MEAN_COEFF = 1.0f, SCALE_COEFF = 10.0f

typedef _Float16 f16x8 __attribute__((ext_vector_type(8)));
typedef float    f32x4 __attribute__((ext_vector_type(4)));
typedef _Float16 half_t;

#define KA  (PRE + ENCD + ARNN)    // 1792   layout: [xpre | ctx | ah]
#define KAQ (KA / 4)               // 448
#define NMA (KAQ / 32)             // 14
#define KD  (ARNN + ENCD + DRNN)   // 2560   layout: [ah | ctx | dh]
#define KDQ (KD / 4)               // 640
#define NMD (KDQ / 32)             // 20
#define LDA_A 1800                 // KA + 8 pad
#define LDA_D 2568                 // KD + 8 pad

// ---- agent-scope (cross-XCD) access: sc1 bypasses the non-coherent per-XCD
// L2 to the L3 coherence point. Mutable cross-block data: sc1 loads+stores.
// Read-only data: plain loads (L2-hot).
__device__ __forceinline__ void st_agent_f32(float* p, float v) {
    __hip_atomic_store(p, v, __ATOMIC_RELAXED, __HIP_MEMORY_SCOPE_AGENT);
}
__device__ __forceinline__ void st_agent_u64(unsigned long long* p, unsigned long long v) {
    __hip_atomic_store(p, v, __ATOMIC_RELAXED, __HIP_MEMORY_SCOPE_AGENT);
}
__device__ __forceinline__ float ld_agent_f32(const float* p) {
    return __hip_atomic_load(p, __ATOMIC_RELAXED, __HIP_MEMORY_SCOPE_AGENT);
}
__device__ __forceinline__ unsigned long long ld_agent_u64(const unsigned long long* p) {
    return __hip_atomic_load(p, __ATOMIC_RELAXED, __HIP_MEMORY_SCOPE_AGENT);
}
__device__ __forceinline__ f16x8 ld_agent_f16x8(const half_t* p) {
    union { unsigned long long u[2]; f16x8 v; } c;
    c.u[0] = __hip_atomic_load((const unsigned long long*)p,
                               __ATOMIC_RELAXED, __HIP_MEMORY_SCOPE_AGENT);
    c.u[1] = __hip_atomic_load(((const unsigned long long*)p) + 1,
                               __ATOMIC_RELAXED, __HIP_MEMORY_SCOPE_AGENT);
    return c.v;
}
// Pin a prefetched fragment (guide rule #17).
__device__ __forceinline__ void keep16(f16x8& v) { asm volatile("" : "+v"(v)); }

// ---------------------------------------------------------------------------
// One-time weight packing / conversion kernels
// ---------------------------------------------------------------------------
template<int KIH, int KHH>
__global__ __launch_bounds__(256) void conv_lstm_w(
    const float* __restrict__ Wih, const float* __restrict__ Whh,
    const float* __restrict__ bih, const float* __restrict__ bhh,
    half_t* __restrict__ Wcat, float* __restrict__ bsum)
{
    constexpr int K = KIH + KHH;
    const int j = blockIdx.x;
    const float* srcA = Wih + (size_t)j * KIH;
    const float* srcB = Whh + (size_t)j * KHH;
    half_t* dst = Wcat + (size_t)j * K;
    for (int k = threadIdx.x; k < KIH; k += 256) dst[k]       = (half_t)srcA[k];
    for (int k = threadIdx.x; k < KHH; k += 256) dst[KIH + k] = (half_t)srcB[k];
    if (threadIdx.x == 0) bsum[j] = bih[j] + bhh[j];
}

__global__ __launch_bounds__(256) void conv_mat(
    const float* __restrict__ src, half_t* __restrict__ dst, int n)
{
    for (int i = blockIdx.x * 256 + threadIdx.x; i < n; i += gridDim.x * 256)
        dst[i] = (half_t)src[i];
}

// ---------------------------------------------------------------------------
// Prenet (one-time, parallel over T*B rows): f16 output (T,B,PRE)
// ---------------------------------------------------------------------------
__global__ __launch_bounds__(256) void prenet_kernel(
    const float* __restrict__ din,
    const float* __restrict__ pW1, const float* __restrict__ pb1,
    const float* __restrict__ pW2, const float* __restrict__ pb2,
    half_t* __restrict__ xpre)
{
    __shared__ float xs[8][EMBD];
    __shared__ float h1s[8][PRE];
    const int tid = threadIdx.x;
    const int row0 = blockIdx.x * 8;

    for (int idx = tid; idx < 8 * EMBD; idx += 256) {
        int r = idx >> 9;
        int e = idx & 511;
        int rid = row0 + r;
        int t = rid >> 5;
        int b = rid & 31;
        float v = 0.f;
        if (t > 0) v = din[(size_t)b * EMBD * Tsteps + (size_t)e * Tsteps + (t - 1)];
        xs[r][e] = v;
    }
    __syncthreads();

    {
        float acc[8] = {0.f,0.f,0.f,0.f,0.f,0.f,0.f,0.f};
        const float* wr = pW1 + (size_t)tid * EMBD;
        for (int e = 0; e < EMBD; e += 4) {
            float4 wv = *(const float4*)(wr + e);
            #pragma unroll
            for (int r = 0; r < 8; ++r) {
                float4 xv = *(const float4*)&xs[r][e];
                acc[r] += wv.x * xv.x + wv.y * xv.y + wv.z * xv.z + wv.w * xv.w;
            }
        }
        float bias = pb1[tid];
        #pragma unroll
        for (int r = 0; r < 8; ++r) h1s[r][tid] = fmaxf(acc[r] + bias, 0.f);
    }
    __syncthreads();

    {
        float acc[8] = {0.f,0.f,0.f,0.f,0.f,0.f,0.f,0.f};
        const float* wr = pW2 + (size_t)tid * PRE;
        for (int e = 0; e < PRE; e += 4) {
            float4 wv = *(const float4*)(wr + e);
            #pragma unroll
            for (int r = 0; r < 8; ++r) {
                float4 xv = *(const float4*)&h1s[r][e];
                acc[r] += wv.x * xv.x + wv.y * xv.y + wv.z * xv.z + wv.w * xv.w;
            }
        }
        float bias = pb2[tid];
        #pragma unroll
        for (int r = 0; r < 8; ++r) {
            int rid = row0 + r;
            int t = rid >> 5;
            int b = rid & 31;
            xpre[(size_t)t * Bsz * PRE + (size_t)b * PRE + tid] =
                (half_t)fmaxf(acc[r] + bias, 0.f);
        }
    }
}

// ---------------------------------------------------------------------------
// Persistent decoder (cooperative). 256 blocks x 512 threads, 1 block/CU.
// Weights in LDS all 400 steps. grid.sync() for both barriers.
// Pipeline (2 syncs/step):
//   ph1: aLSTM_t || dLSTM_{t-1} || outproj_{t-2} (+attention partials)
//   ph2: att_t
// Non-ctx B-fragments for the next ph1 are issued (and keep16-pinned) just
// BEFORE the second grid.sync — they drain during the sync; ctx tails after.
// ---------------------------------------------------------------------------
__global__ __launch_bounds__(512, 2) void decoder_persistent(
    const half_t* __restrict__ Wcat_a, const float* __restrict__ bsum_a,
    const half_t* __restrict__ Wcat_d, const float* __restrict__ bsum_d,
    const half_t* __restrict__ Wo, const float* __restrict__ ob,
    const half_t* __restrict__ xpre,
    const float* __restrict__ attWp, const float* __restrict__ attbp,
    const int* __restrict__ mlen, const half_t* __restrict__ mem16,
    half_t* __restrict__ ah0, half_t* __restrict__ ah1,
    half_t* __restrict__ dh0, half_t* __restrict__ dh1,
    half_t* __restrict__ ctx0, half_t* __restrict__ ctx1,
    float* __restrict__ mean0, float* __restrict__ mean1,
    float* __restrict__ partials,   // [32][256][2] f32
    float* __restrict__ logits, float* __restrict__ aligns,
    float* __restrict__ ps)
{
    cg::grid_group grid = cg::this_grid();

    const int blk   = blockIdx.x;
    const int tid   = threadIdx.x;
    const int wave  = tid >> 6;
    const int lane  = tid & 63;
    const int btile = wave & 1;
    const int kq    = wave >> 1;
    const int m15   = lane & 15;
    const int kh    = lane >> 4;
    const int u0    = blk << 2;
    const int bb    = (btile << 4) + m15;

    __shared__ __align__(16) half_t wAl[16 * LDA_A];   // 57.6 KB
    __shared__ __align__(16) half_t wDl[16 * LDA_D];   // 82.2 KB
    __shared__ float gredA[4][2][16][16];              // 8 KB
    __shared__ float gredD[4][2][16][16];              // 8 KB
    __shared__ float wsh[Lmem];                        // 2 KB
    __shared__ float lred[16][33];                     // 2.1 KB
    __shared__ float part[4][32][2];                   // 1 KB
    __shared__ float wred8[8][2];
    __shared__ float bc2[2];

    // ---- stage weight rows into LDS (one-time) ----
    for (int g = tid; g < 16 * (KA / 8); g += 512) {
        int r = g / (KA / 8);
        int c = (g - r * (KA / 8)) * 8;
        int jr = (r >> 2) * 1024 + u0 + (r & 3);
        *(f16x8*)(wAl + r * LDA_A + c) = *(const f16x8*)(Wcat_a + (size_t)jr * KA + c);
    }
    for (int g = tid; g < 16 * (KD / 8); g += 512) {
        int r = g / (KD / 8);
        int c = (g - r * (KD / 8)) * 8;
        int jr = (r >> 2) * 1024 + u0 + (r & 3);
        *(f16x8*)(wDl + r * LDA_D + c) = *(const f16x8*)(Wcat_d + (size_t)jr * KD + c);
    }
    // epilogue biases + attWp slice: A -> threads 0..127, D -> 128..255
    float bsA[4] = {0.f,0.f,0.f,0.f}, bsD[4] = {0.f,0.f,0.f,0.f};
    float wp0 = 0.f, wp1 = 0.f;
    float cA = 0.f, cD = 0.f;
    if (tid < 128) {
        const int ul = tid >> 5;
        #pragma unroll
        for (int gi = 0; gi < 4; ++gi) bsA[gi] = bsum_a[gi * 1024 + u0 + ul];
        wp0 = attWp[u0 + ul];
        wp1 = attWp[ARNN + u0 + ul];
    } else if (tid < 256) {
        const int ul = (tid - 128) >> 5;
        #pragma unroll
        for (int gi = 0; gi < 4; ++gi) bsD[gi] = bsum_d[gi * 1024 + u0 + ul];
    }
    const half_t* lA = wAl + m15 * LDA_A + kq * KAQ + (kh << 3);
    const half_t* lD = wDl + m15 * LDA_D + kq * KDQ + (kh << 3);
    __syncthreads();

    // ---- initial bvA load for t=0 (ctx1/ah1 zeroed; xpre plain) ----
    f16x8 bvA[NMA], bvD[NMD];
    {
        const half_t* s0 = xpre;
        #pragma unroll
        for (int i = 0; i < NMA; ++i) {
            const int kg = kq * KAQ + i * 32 + (kh << 3);
            if (kg < PRE)             bvA[i] = *(const f16x8*)(s0 + bb * PRE + kg);
            else if (kg < PRE + ENCD) bvA[i] = ld_agent_f16x8(ctx1 + bb * ENCD + (kg - PRE));
            else                      bvA[i] = ld_agent_f16x8(ah1 + bb * ARNN + (kg - PRE - ENCD));
        }
    }

    for (int t = 0; t <= Tsteps + 1; ++t) {
        const int par = t & 1;
        half_t*       ah_cur  = par ? ah1 : ah0;
        half_t*       ctx_cur = par ? ctx1 : ctx0;   // ctx_{t-2} during ph1; ctx_t after ph2
        float*        mn_cur  = par ? mean1 : mean0;
        const float*  mn_prv  = par ? mean0 : mean1;
        half_t*       dh_s    = par ? dh0 : dh1;     // dh_{t-1} written in ph1
        const half_t* dh_prv  = par ? dh1 : dh0;     // dh_{t-2}

        // ========== PHASE 1: aLSTM_t || dLSTM_{t-1} || outproj_{t-2} =======
        if (t < Tsteps) {
            f32x4 accA = {0.f,0.f,0.f,0.f};
            #pragma unroll
            for (int i = 0; i < NMA; ++i) {
                f16x8 av = *(const f16x8*)(lA + i * 32);
                accA = __builtin_amdgcn_mfma_f32_16x16x32_f16(av, bvA[i], accA, 0, 0, 0);
            }
            #pragma unroll
            for (int r = 0; r < 4; ++r)
                gredA[kq][btile][(kh << 2) + r][m15] = accA[r];
        }
        if (t >= 1 && t <= Tsteps) {
            f32x4 accD = {0.f,0.f,0.f,0.f};
            #pragma unroll
            for (int i = 0; i < NMD; ++i) {
                f16x8 av = *(const f16x8*)(lD + i * 32);
                accD = __builtin_amdgcn_mfma_f32_16x16x32_f16(av, bvD[i], accD, 0, 0, 0);
            }
            #pragma unroll
            for (int r = 0; r < 4; ++r)
                gredD[kq][btile][(kh << 2) + r][m15] = accD[r];
        }
        if (t >= 2) {
            // outproj for step t-2: row n = blk; acts = dh_{t-2} | ctx_{t-2}
            const int b_o = tid & 31;
            const int ks  = tid >> 5;
            const half_t* wrow = Wo + (size_t)blk * (DRNN + ENCD) + ks * 96;
            float outacc = 0.f;
            #pragma unroll
            for (int hf = 0; hf < 2; ++hf) {
                f16x8 wv[6], av[6];
                #pragma unroll
                for (int c8 = 0; c8 < 6; ++c8) {
                    const int cc = hf * 6 + c8;
                    const int k = ks * 96 + cc * 8;
                    wv[c8] = *(const f16x8*)(wrow + cc * 8);   // plain, L2-hot
                    const half_t* ap = (k < DRNN) ? (dh_prv + b_o * DRNN + k)
                                                  : (ctx_cur + b_o * ENCD + (k - DRNN));
                    av[c8] = ld_agent_f16x8(ap);
                }
                #pragma unroll
                for (int c8 = 0; c8 < 6; ++c8)
                    #pragma unroll
                    for (int e = 0; e < 8; ++e)
                        outacc += (float)wv[c8][e] * (float)av[c8][e];
            }
            lred[ks][b_o] = outacc;
        }
        __syncthreads();
        // concurrent epilogues
        if (tid < 128) {
            if (t < Tsteps) {
                const int ul = tid >> 5;
                const int bq = tid & 31;
                const int bt = bq >> 4;
                const int nn = bq & 15;
                float g[4];
                #pragma unroll
                for (int gi = 0; gi < 4; ++gi) {
                    const int mr = (gi << 2) + ul;
                    g[gi] = gredA[0][bt][mr][nn] + gredA[1][bt][mr][nn]
                          + gredA[2][bt][mr][nn] + gredA[3][bt][mr][nn] + bsA[gi];
                }
                float si = 1.f / (1.f + expf(-g[0]));
                float sf = 1.f / (1.f + expf(-g[1]));
                float so = 1.f / (1.f + expf(-g[3]));
                cA = sf * cA + si * tanhf(g[2]);
                float hval = so * tanhf(cA);
                hstA_store:
                part[ul][bq][0] = hval * wp0;
                part[ul][bq][1] = hval * wp1;
                st_agent_u64  // placeholder comment removed below
                ;
                // scattered 2B stores avoided: stage via part; publish below
                ((half_t*)wred8)[0] = (half_t)0;  // no-op to keep structure
                // direct store (same as R10):
                __hip_atomic_store((unsigned short*)&ah_cur[bq * 1024 + u0 + ul],
                                   __builtin_bit_cast(unsigned short, (half_t)hval),
                                   __ATOMIC_RELAXED, __HIP_MEMORY_SCOPE_AGENT);
            }
        } else if (tid < 256) {
            if (t >= 1 && t <= Tsteps) {
                const int lt = tid - 128;
                const int ul = lt >> 5;
                const int bq = lt & 31;
                const int bt = bq >> 4;
                const int nn = bq & 15;
                float g[4];
                #pragma unroll
                for (int gi = 0; gi < 4; ++gi) {
                    const int mr = (gi << 2) + ul;
                    g[gi] = gredD[0][bt][mr][nn] + gredD[1][bt][mr][nn]
                          + gredD[2][bt][mr][nn] + gredD[3][bt][mr][nn] + bsD[gi];
                }
                float si = 1.f / (1.f + expf(-g[0]));
                float sf = 1.f / (1.f + expf(-g[1]));
                float so = 1.f / (1.f + expf(-g[3]));
                cD = sf * cD + si * tanhf(g[2]);
                __hip_atomic_store((unsigned short*)&dh_s[bq * 1024 + u0 + ul],
                                   __builtin_bit_cast(unsigned short, (half_t)(so * tanhf(cD))),
                                   __ATOMIC_RELAXED, __HIP_MEMORY_SCOPE_AGENT);
            }
        } else if (tid < 288) {
            if (t >= 2) {
                const int b = tid - 256;
                float s = 0.f;
                #pragma unroll
                for (int q = 0; q < 16; ++q) s += lred[q][b];
                st_agent_f32(&logits[(size_t)b * Tsteps * NSYM + (size_t)(t - 2) * NSYM + blk],
                             s + ob[blk]);
            }
        }
        __syncthreads();
        if (t < Tsteps && tid < 32) {
            float p0 = part[0][tid][0] + part[1][tid][0] + part[2][tid][0] + part[3][tid][0];
            float p1 = part[0][tid][1] + part[1][tid][1] + part[2][tid][1] + part[3][tid][1];
            union { float2 f; unsigned long long u; } pp;
            pp.f.x = p0; pp.f.y = p1;
            st_agent_u64((unsigned long long*)(partials + ((size_t)tid * 256 + blk) * 2), pp.u);
        }
        if (t <= Tsteps) grid.sync();   // ---- BARRIER 1 ----

        // ================= PHASE 2: att_t ==================================
        if (t < Tsteps) {
            const int abt = blk >> 3;   // batch
            const int dt  = blk & 7;    // d-tile
            float p0 = 0.f, p1 = 0.f;
            if (tid < 256) {
                union { unsigned long long u; float2 f; } pv;
                pv.u = ld_agent_u64((const unsigned long long*)(partials + ((size_t)abt * 256 + tid) * 2));
                p0 = pv.f.x; p1 = pv.f.y;
            }
            #pragma unroll
            for (int off = 32; off > 0; off >>= 1) {
                p0 += __shfl_down(p0, off, 64);
                p1 += __shfl_down(p1, off, 64);
            }
            if (lane == 0) { wred8[wave][0] = p0; wred8[wave][1] = p1; }
            __syncthreads();
            if (tid == 0) {
                float q0 = attbp[0], q1 = attbp[1];
                #pragma unroll
                for (int w = 0; w < 8; ++w) { q0 += wred8[w][0]; q1 += wred8[w][1]; }
                float mn = ld_agent_f32(&mn_prv[abt]) + expf(q0) * 1.0f;  // MEAN_COEFF
                float sc = expf(q1) * 10.0f;                              // SCALE_COEFF
                if (dt == 0) {
                    st_agent_f32(&mn_cur[abt], mn);
                    st_agent_f32(&ps[(size_t)abt * Tsteps * 2 + (size_t)t * 2 + 0], q0);
                    st_agent_f32(&ps[(size_t)abt * Tsteps * 2 + (size_t)t * 2 + 1], q1);
                }
                bc2[0] = mn; bc2[1] = sc;
            }
            __syncthreads();
            const float mn = bc2[0], sc = bc2[1];
            const float inv_s = 1.f / sc;
            const float coef = 0.3989422804014327f * inv_s;
            const int len = mlen[abt];
            {
                float z = ((float)tid - mn) * inv_s;
                wsh[tid] = (tid < len) ? expf(-0.5f * z * z) * coef : 0.f;
            }
            __syncthreads();
            if (tid < 64) {
                const int l = (dt << 6) + tid;
                st_agent_f32(&aligns[(size_t)abt * Tsteps * Lmem + (size_t)t * Lmem + l], wsh[l]);
            }
            int lo = (int)fmaxf(0.f, floorf(mn - 9.f * sc));
            int hi = (int)fminf((float)len, ceilf(mn + 9.f * sc) + 1.f);
            const int d8 = (dt << 6) + (wave << 3);
            const half_t* mb = mem16 + (size_t)abt * Lmem * ENCD + d8;
            float acc[8] = {0.f,0.f,0.f,0.f,0.f,0.f,0.f,0.f};
            for (int l = lo + lane; l < hi; l += 64) {
                f16x8 mv = *(const f16x8*)(mb + (size_t)l * ENCD);   // plain, L2-hot
                float w = wsh[l];
                #pragma unroll
                for (int j = 0; j < 8; ++j) acc[j] += w * (float)mv[j];
            }
            #pragma unroll
            for (int off = 32; off > 0; off >>= 1) {
                #pragma unroll
                for (int j = 0; j < 8; ++j) acc[j] += __shfl_down(acc[j], off, 64);
            }
            if (lane == 0) {
                union { unsigned long long u; half_t h[4]; } pk0, pk1;
                #pragma unroll
                for (int j = 0; j < 4; ++j) { pk0.h[j] = (half_t)acc[j]; pk1.h[j] = (half_t)acc[4 + j]; }
                st_agent_u64((unsigned long long*)(ctx_cur + abt * ENCD + d8), pk0.u);
                st_agent_u64((unsigned long long*)(ctx_cur + abt * ENCD + d8 + 4), pk1.u);
            }

            // ---- prefetch non-ctx fragments for next ph1 (drain in sync) ----
            if (t + 1 < Tsteps) {
                const half_t* s0n = xpre + (size_t)(t + 1) * Bsz * PRE;
                #pragma unroll
                for (int i = 0; i < NMA; ++i) {
                    const int kg = kq * KAQ + i * 32 + (kh << 3);
                    if (kg < PRE)
                        bvA[i] = *(const f16x8*)(s0n + bb * PRE + kg);
                    else if (kg >= PRE + ENCD)
                        bvA[i] = ld_agent_f16x8(ah_cur + bb * ARNN + (kg - PRE - ENCD));
                }
            }
            #pragma unroll
            for (int i = 0; i < NMD; ++i) {
                const int kg = kq * KDQ + i * 32 + (kh << 3);
                if (kg < ARNN)
                    bvD[i] = ld_agent_f16x8(ah_cur + bb * ARNN + kg);
                else if (kg >= ARNN + ENCD)
                    bvD[i] = ld_agent_f16x8(dh_s + bb * DRNN + (kg - ARNN - ENCD));
            }
            #pragma unroll
            for (int i = 0; i < NMA; ++i) keep16(bvA[i]);
            #pragma unroll
            for (int i = 0; i < NMD; ++i) keep16(bvD[i]);

            grid.sync();   // ---- BARRIER 2 ----

            // post-sync: ctx_t segments (the only ph2-produced input)
            if (t + 1 < Tsteps) {
                #pragma unroll
                for (int i = 0; i < NMA; ++i) {
                    const int kg = kq * KAQ + i * 32 + (kh << 3);
                    if (kg >= PRE && kg < PRE + ENCD)
                        bvA[i] = ld_agent_f16x8(ctx_cur + bb * ENCD + (kg - PRE));
                }
            }
            #pragma unroll
            for (int i = 0; i < NMD; ++i) {
                const int kg = kq * KDQ + i * 32 + (kh << 3);
                if (kg >= ARNN && kg < ARNN + ENCD)
                    bvD[i] = ld_agent_f16x8(ctx_cur + bb * ENCD + (kg - ARNN));
            }
        }
    }
}

// ---------------------------------------------------------------------------
extern "C" void kernel_launch(void* const* d_in, const int* in_sizes, int n_in,
                              void* d_out, int out_size, void* d_ws, size_t ws_size,
                              hipStream_t stream)
{
    (void)in_sizes; (void)n_in; (void)out_size; (void)ws_size;
    const float* memory = (const float*)d_in[0];
    const float* din    = (const float*)d_in[1];
    const int*   mlen   = (const int*)d_in[2];
    const float* pW1    = (const float*)d_in[3];
    const float* pb1    = (const float*)d_in[4];
    const float* pW2    = (const float*)d_in[5];
    const float* pb2    = (const float*)d_in[6];
    const float* aWih   = (const float*)d_in[7];
    const float* aWhh   = (const float*)d_in[8];
    const float* abih   = (const float*)d_in[9];
    const float* abhh   = (const float*)d_in[10];
    const float* attWp  = (const float*)d_in[11];
    const float* attbp  = (const float*)d_in[12];
    const float* dWih   = (const float*)d_in[13];
    const float* dWhh   = (const float*)d_in[14];
    const float* dbih   = (const float*)d_in[15];
    const float* dbhh   = (const float*)d_in[16];
    const float* oW     = (const float*)d_in[17];
    const float* ob     = (const float*)d_in[18];

    float* logits = (float*)d_out;
    float* aligns = logits + (size_t)Bsz * Tsteps * NSYM;
    float* ps     = aligns + (size_t)Bsz * Tsteps * Lmem;

    char* base = (char*)d_ws;
    auto alloc = [&](size_t bytes) -> char* {
        char* p = base; base += (bytes + 255) & ~(size_t)255; return p;
    };
    half_t* Wcat_a = (half_t*)alloc((size_t)4096 * KA * 2);
    half_t* Wcat_d = (half_t*)alloc((size_t)4096 * KD * 2);
    half_t* Wo     = (half_t*)alloc((size_t)NSYM * (DRNN + ENCD) * 2);
    float*  bsum_a = (float*)alloc(4096 * 4);
    float*  bsum_d = (float*)alloc(4096 * 4);
    half_t* xpre   = (half_t*)alloc((size_t)Tsteps * Bsz * PRE * 2);
    half_t* mem16  = (half_t*)alloc((size_t)Bsz * Lmem * ENCD * 2);
    half_t* ah0    = (half_t*)alloc(Bsz * ARNN * 2);
    half_t* ah1    = (half_t*)alloc(Bsz * ARNN * 2);
    half_t* dh0    = (half_t*)alloc(Bsz * DRNN * 2);
    half_t* dh1    = (half_t*)alloc(Bsz * DRNN * 2);
    half_t* ctx0   = (half_t*)alloc(Bsz * ENCD * 2);
    half_t* ctx1   = (half_t*)alloc(Bsz * ENCD * 2);
    float*  mean0  = (float*)alloc(Bsz * 4);
    float*  mean1  = (float*)alloc(Bsz * 4);
    float*  partials = (float*)alloc((size_t)Bsz * 256 * 2 * 4);

    (void)hipMemsetAsync(ah1,   0, Bsz * ARNN * 2, stream);
    (void)hipMemsetAsync(dh1,   0, Bsz * DRNN * 2, stream);
    (void)hipMemsetAsync(ctx1,  0, Bsz * ENCD * 2, stream);
    (void)hipMemsetAsync(mean0, 0, Bsz * 4, stream);
    (void)hipMemsetAsync(mean1, 0, Bsz * 4, stream);

    conv_lstm_w<PRE + ENCD, ARNN><<<4096, 256, 0, stream>>>(
        aWih, aWhh, abih, abhh, Wcat_a, bsum_a);
    conv_lstm_w<ARNN + ENCD, DRNN><<<4096, 256, 0, stream>>>(
        dWih, dWhh, dbih, dbhh, Wcat_d, bsum_d);
    conv_mat<<<768, 256, 0, stream>>>(oW, Wo, NSYM * (DRNN + ENCD));
    conv_mat<<<4096, 256, 0, stream>>>(memory, mem16, Bsz * Lmem * ENCD);
    prenet_kernel<<<Tsteps * Bsz / 8, 256, 0, stream>>>(din, pW1, pb1, pW2, pb2, xpre);

    // cooperative launch: grid.sync() inside
    void* args[] = {
        (void*)&Wcat_a, (void*)&bsum_a, (void*)&Wcat_d, (void*)&bsum_d,
        (void*)&Wo, (void*)&ob, (void*)&xpre, (void*)&attWp, (void*)&attbp,
        (void*)&mlen, (void*)&mem16,
        (void*)&ah0, (void*)&ah1, (void*)&dh0, (void*)&dh1,
        (void*)&ctx0, (void*)&ctx1, (void*)&mean0, (void*)&mean1,
        (void*)&partials, (void*)&logits, (void*)&aligns, (void*)&ps
    };
    (void)hipLaunchCooperativeKernel((void*)decoder_persistent,
                                     dim3(256), dim3(512), args, 0, stream);
}

// Round 15
// 14313.039 us; speedup vs baseline: 2.5119x; 2.5119x over previous
//
#include <hip/hip_runtime.h>
#include <math.h>

// Problem constants (from reference)
#define Bsz   32
#define Lmem  512
#define Tsteps 400
#define EMBD  512
#define PRE   256
#define ENCD  512
#define ARNN  1024
#define DRNN  1024
#define NSYM  256
// MEAN_COEFF = 1.0f, SCALE_COEFF = 10.0f

typedef _Float16 f16x8 __attribute__((ext_vector_type(8)));
typedef float    f32x4 __attribute__((ext_vector_type(4)));
typedef _Float16 half_t;

#define KA  (PRE + ENCD + ARNN)    // 1792
#define KAQ (KA / 4)               // 448
#define NMA (KAQ / 32)             // 14
#define KD  (ARNN + ENCD + DRNN)   // 2560
#define KDQ (KD / 4)               // 640
#define NMD (KDQ / 32)             // 20
#define LDA_A 1800                 // KA + 8 pad
#define LDA_D 2568                 // KD + 8 pad

// ---- agent-scope (cross-XCD) access: sc1 bypasses the non-coherent per-XCD
// L2. Mutable cross-block data: sc1 loads+stores. Read-only data: plain loads
// (L2-hot). No cache-invalidate fences anywhere.
__device__ __forceinline__ void st_agent_f16(half_t* p, half_t v) {
    __hip_atomic_store((unsigned short*)p, __builtin_bit_cast(unsigned short, v),
                       __ATOMIC_RELAXED, __HIP_MEMORY_SCOPE_AGENT);
}
__device__ __forceinline__ void st_agent_f32(float* p, float v) {
    __hip_atomic_store(p, v, __ATOMIC_RELAXED, __HIP_MEMORY_SCOPE_AGENT);
}
__device__ __forceinline__ void st_agent_u32(unsigned* p, unsigned v) {
    __hip_atomic_store(p, v, __ATOMIC_RELAXED, __HIP_MEMORY_SCOPE_AGENT);
}
__device__ __forceinline__ float ld_agent_f32(const float* p) {
    return __hip_atomic_load(p, __ATOMIC_RELAXED, __HIP_MEMORY_SCOPE_AGENT);
}
__device__ __forceinline__ unsigned ld_agent_u32(const unsigned* p) {
    return __hip_atomic_load(p, __ATOMIC_RELAXED, __HIP_MEMORY_SCOPE_AGENT);
}
__device__ __forceinline__ f16x8 ld_agent_f16x8(const half_t* p) {
    union { unsigned long long u[2]; f16x8 v; } c;
    c.u[0] = __hip_atomic_load((const unsigned long long*)p,
                               __ATOMIC_RELAXED, __HIP_MEMORY_SCOPE_AGENT);
    c.u[1] = __hip_atomic_load(((const unsigned long long*)p) + 1,
                               __ATOMIC_RELAXED, __HIP_MEMORY_SCOPE_AGENT);
    return c.v;
}
// Pin a prefetched fragment (guide rule #17): register-constraint use the
// compiler cannot sink — forces the load issued & retired here.
__device__ __forceinline__ void keep16(f16x8& v) { asm volatile("" : "+v"(v)); }

// ---------------------------------------------------------------------------
// One-time weight packing / conversion kernels
// ---------------------------------------------------------------------------
template<int KIH, int KHH>
__global__ __launch_bounds__(256) void conv_lstm_w(
    const float* __restrict__ Wih, const float* __restrict__ Whh,
    const float* __restrict__ bih, const float* __restrict__ bhh,
    half_t* __restrict__ Wcat, float* __restrict__ bsum)
{
    constexpr int K = KIH + KHH;
    const int j = blockIdx.x;
    const float* srcA = Wih + (size_t)j * KIH;
    const float* srcB = Whh + (size_t)j * KHH;
    half_t* dst = Wcat + (size_t)j * K;
    for (int k = threadIdx.x; k < KIH; k += 256) dst[k]       = (half_t)srcA[k];
    for (int k = threadIdx.x; k < KHH; k += 256) dst[KIH + k] = (half_t)srcB[k];
    if (threadIdx.x == 0) bsum[j] = bih[j] + bhh[j];
}

__global__ __launch_bounds__(256) void conv_mat(
    const float* __restrict__ src, half_t* __restrict__ dst, int n)
{
    for (int i = blockIdx.x * 256 + threadIdx.x; i < n; i += gridDim.x * 256)
        dst[i] = (half_t)src[i];
}

// ---------------------------------------------------------------------------
// Prenet (one-time, parallel over T*B rows): f16 output (T,B,PRE)
// ---------------------------------------------------------------------------
__global__ __launch_bounds__(256) void prenet_kernel(
    const float* __restrict__ din,
    const float* __restrict__ pW1, const float* __restrict__ pb1,
    const float* __restrict__ pW2, const float* __restrict__ pb2,
    half_t* __restrict__ xpre)
{
    __shared__ float xs[8][EMBD];
    __shared__ float h1s[8][PRE];
    const int tid = threadIdx.x;
    const int row0 = blockIdx.x * 8;

    for (int idx = tid; idx < 8 * EMBD; idx += 256) {
        int r = idx >> 9;
        int e = idx & 511;
        int rid = row0 + r;
        int t = rid >> 5;
        int b = rid & 31;
        float v = 0.f;
        if (t > 0) v = din[(size_t)b * EMBD * Tsteps + (size_t)e * Tsteps + (t - 1)];
        xs[r][e] = v;
    }
    __syncthreads();

    {
        float acc[8] = {0.f,0.f,0.f,0.f,0.f,0.f,0.f,0.f};
        const float* wr = pW1 + (size_t)tid * EMBD;
        for (int e = 0; e < EMBD; e += 4) {
            float4 wv = *(const float4*)(wr + e);
            #pragma unroll
            for (int r = 0; r < 8; ++r) {
                float4 xv = *(const float4*)&xs[r][e];
                acc[r] += wv.x * xv.x + wv.y * xv.y + wv.z * xv.z + wv.w * xv.w;
            }
        }
        float bias = pb1[tid];
        #pragma unroll
        for (int r = 0; r < 8; ++r) h1s[r][tid] = fmaxf(acc[r] + bias, 0.f);
    }
    __syncthreads();

    {
        float acc[8] = {0.f,0.f,0.f,0.f,0.f,0.f,0.f,0.f};
        const float* wr = pW2 + (size_t)tid * PRE;
        for (int e = 0; e < PRE; e += 4) {
            float4 wv = *(const float4*)(wr + e);
            #pragma unroll
            for (int r = 0; r < 8; ++r) {
                float4 xv = *(const float4*)&h1s[r][e];
                acc[r] += wv.x * xv.x + wv.y * xv.y + wv.z * xv.z + wv.w * xv.w;
            }
        }
        float bias = pb2[tid];
        #pragma unroll
        for (int r = 0; r < 8; ++r) {
            int rid = row0 + r;
            int t = rid >> 5;
            int b = rid & 31;
            xpre[(size_t)t * Bsz * PRE + (size_t)b * PRE + tid] =
                (half_t)fmaxf(acc[r] + bias, 0.f);
        }
    }
}

// ---------------------------------------------------------------------------
// Split-phase RMW-free device barrier (256 blocks). arrive = drain stores +
// block barrier + tid0 sc1 flag store. wait = 64 pollers x 4 relaxed sc1
// flag loads + block barrier. Prefetch loads go between arrive and wait.
// ---------------------------------------------------------------------------
__device__ __forceinline__ void g_arrive(unsigned* flags, unsigned ph)
{
    asm volatile("s_waitcnt vmcnt(0)" ::: "memory");
    __syncthreads();
    if (threadIdx.x == 0)
        __hip_atomic_store(flags + blockIdx.x * 16, ph,
                           __ATOMIC_RELAXED, __HIP_MEMORY_SCOPE_AGENT);
}
__device__ __forceinline__ void g_wait(unsigned* flags, unsigned ph)
{
    if (threadIdx.x < 64) {
        const unsigned* f = flags + threadIdx.x * 64;
        for (;;) {
            unsigned a = ld_agent_u32(f);
            unsigned b = ld_agent_u32(f + 16);
            unsigned c = ld_agent_u32(f + 32);
            unsigned d = ld_agent_u32(f + 48);
            if (min(min(a, b), min(c, d)) >= ph) break;
            __builtin_amdgcn_s_sleep(2);
        }
    }
    __syncthreads();
}

// ---------------------------------------------------------------------------
// Persistent decoder. 256 blocks x 512 threads. Weights in LDS all 400 steps.
// 2 barriers/step; next phase1's B-fragments prefetched (keep16-pinned)
// between arrive(ph2) and wait(ph2); ctx segment loads post-wait.
// Concurrent aLSTM/dLSTM epilogues (threads 0-127 / 128-255).
// ---------------------------------------------------------------------------
__global__ __launch_bounds__(512, 1) void decoder_persistent(
    const half_t* __restrict__ Wcat_a, const float* __restrict__ bsum_a,
    const half_t* __restrict__ Wcat_d, const float* __restrict__ bsum_d,
    const half_t* __restrict__ Wo, const float* __restrict__ ob,
    const half_t* __restrict__ xpre,
    const float* __restrict__ attWp, const float* __restrict__ attbp,
    const int* __restrict__ mlen, const half_t* __restrict__ mem16,
    half_t* __restrict__ ah0, half_t* __restrict__ ah1,
    half_t* __restrict__ dh0, half_t* __restrict__ dh1,
    half_t* __restrict__ ctx0, half_t* __restrict__ ctx1,
    float* __restrict__ mean0, float* __restrict__ mean1,
    float* __restrict__ logits, float* __restrict__ aligns,
    float* __restrict__ ps,
    unsigned* flags)
{
    const int blk   = blockIdx.x;
    const int tid   = threadIdx.x;
    const int wave  = tid >> 6;
    const int lane  = tid & 63;
    const int btile = wave & 1;
    const int kq    = wave >> 1;
    const int m15   = lane & 15;
    const int kh    = lane >> 4;
    const int u0    = blk << 2;
    const int bb    = (btile << 4) + m15;

    __shared__ __align__(16) half_t wAl[16 * LDA_A];   // 57.6 KB
    __shared__ __align__(16) half_t wDl[16 * LDA_D];   // 82.2 KB
    __shared__ float gredA[4][2][16][16];              // 8 KB
    __shared__ float gredD[4][2][16][16];              // 8 KB
    __shared__ float wsh[Lmem];                        // 2 KB
    __shared__ float lred[16][33];                     // 2.1 KB
    __shared__ float wred8[8][2];
    __shared__ float bc2[2];

    // ---- stage weight rows into LDS (one-time) ----
    for (int g = tid; g < 16 * (KA / 8); g += 512) {
        int r = g / (KA / 8);
        int c = (g - r * (KA / 8)) * 8;
        int jr = (r >> 2) * 1024 + u0 + (r & 3);
        *(f16x8*)(wAl + r * LDA_A + c) = *(const f16x8*)(Wcat_a + (size_t)jr * KA + c);
    }
    for (int g = tid; g < 16 * (KD / 8); g += 512) {
        int r = g / (KD / 8);
        int c = (g - r * (KD / 8)) * 8;
        int jr = (r >> 2) * 1024 + u0 + (r & 3);
        *(f16x8*)(wDl + r * LDA_D + c) = *(const f16x8*)(Wcat_d + (size_t)jr * KD + c);
    }
    // epilogue biases: A -> threads 0..127, D -> threads 128..255
    float bsA[4] = {0.f,0.f,0.f,0.f}, bsD[4] = {0.f,0.f,0.f,0.f};
    float cA = 0.f, cD = 0.f;
    if (tid < 128) {
        const int ul = tid >> 5;
        #pragma unroll
        for (int gi = 0; gi < 4; ++gi) bsA[gi] = bsum_a[gi * 1024 + u0 + ul];
    } else if (tid < 256) {
        const int ul = (tid - 128) >> 5;
        #pragma unroll
        for (int gi = 0; gi < 4; ++gi) bsD[gi] = bsum_d[gi * 1024 + u0 + ul];
    }
    const half_t* lA = wAl + m15 * LDA_A + kq * KAQ + (kh << 3);
    const half_t* lD = wDl + m15 * LDA_D + kq * KDQ + (kh << 3);
    __syncthreads();

    // ---- initial bvA load for t=0 (ctx1/ah1 zeroed; xpre plain) ----
    f16x8 bvA[NMA], bvD[NMD];
    {
        const half_t* s0 = xpre;
        #pragma unroll
        for (int i = 0; i < NMA; ++i) {
            const int kg = kq * KAQ + i * 32 + (kh << 3);
            if (kg < PRE)             bvA[i] = *(const f16x8*)(s0 + bb * PRE + kg);
            else if (kg < PRE + ENCD) bvA[i] = ld_agent_f16x8(ctx1 + bb * ENCD + (kg - PRE));
            else                      bvA[i] = ld_agent_f16x8(ah1 + bb * ARNN + (kg - PRE - ENCD));
        }
    }

    unsigned ph = 0;

    for (int t = 0; t <= Tsteps; ++t) {
        const int par = t & 1;
        half_t*       ah_cur  = par ? ah1 : ah0;
        half_t*       ctx_cur = par ? ctx1 : ctx0;
        const half_t* ctx_prv = par ? ctx0 : ctx1;
        float*        mn_cur  = par ? mean1 : mean0;
        const float*  mn_prv  = par ? mean0 : mean1;
        half_t*       dh_s    = par ? dh0 : dh1;

        // ================= PHASE 1: aLSTM_t || dLSTM_{t-1} =================
        if (t < Tsteps) {
            f32x4 accA = {0.f,0.f,0.f,0.f};
            #pragma unroll
            for (int i = 0; i < NMA; ++i) {
                f16x8 av = *(const f16x8*)(lA + i * 32);
                accA = __builtin_amdgcn_mfma_f32_16x16x32_f16(av, bvA[i], accA, 0, 0, 0);
            }
            #pragma unroll
            for (int r = 0; r < 4; ++r)
                gredA[kq][btile][(kh << 2) + r][m15] = accA[r];
        }
        if (t > 0) {
            f32x4 accD = {0.f,0.f,0.f,0.f};
            #pragma unroll
            for (int i = 0; i < NMD; ++i) {
                f16x8 av = *(const f16x8*)(lD + i * 32);
                accD = __builtin_amdgcn_mfma_f32_16x16x32_f16(av, bvD[i], accD, 0, 0, 0);
            }
            #pragma unroll
            for (int r = 0; r < 4; ++r)
                gredD[kq][btile][(kh << 2) + r][m15] = accD[r];
        }
        __syncthreads();
        // concurrent epilogues: A on threads 0..127, D on threads 128..255
        if (tid < 128) {
            if (t < Tsteps) {
                const int ul = tid >> 5;
                const int bq = tid & 31;
                const int bt = bq >> 4;
                const int nn = bq & 15;
                float g[4];
                #pragma unroll
                for (int gi = 0; gi < 4; ++gi) {
                    const int mr = (gi << 2) + ul;
                    g[gi] = gredA[0][bt][mr][nn] + gredA[1][bt][mr][nn]
                          + gredA[2][bt][mr][nn] + gredA[3][bt][mr][nn] + bsA[gi];
                }
                float si = 1.f / (1.f + expf(-g[0]));
                float sf = 1.f / (1.f + expf(-g[1]));
                float so = 1.f / (1.f + expf(-g[3]));
                cA = sf * cA + si * tanhf(g[2]);
                st_agent_f16(&ah_cur[bq * 1024 + u0 + ul], (half_t)(so * tanhf(cA)));
            }
        } else if (tid < 256) {
            if (t > 0) {
                const int lt = tid - 128;
                const int ul = lt >> 5;
                const int bq = lt & 31;
                const int bt = bq >> 4;
                const int nn = bq & 15;
                float g[4];
                #pragma unroll
                for (int gi = 0; gi < 4; ++gi) {
                    const int mr = (gi << 2) + ul;
                    g[gi] = gredD[0][bt][mr][nn] + gredD[1][bt][mr][nn]
                          + gredD[2][bt][mr][nn] + gredD[3][bt][mr][nn] + bsD[gi];
                }
                float si = 1.f / (1.f + expf(-g[0]));
                float sf = 1.f / (1.f + expf(-g[1]));
                float so = 1.f / (1.f + expf(-g[3]));
                cD = sf * cD + si * tanhf(g[2]);
                st_agent_f16(&dh_s[bq * 1024 + u0 + ul], (half_t)(so * tanhf(cD)));
            }
        }
        ++ph; g_arrive(flags, ph); g_wait(flags, ph);

        // ================= PHASE 2: att_t || outproj_{t-1} =================
        if (t < Tsteps) {
            const int abt = blk >> 3;   // batch
            const int dt  = blk & 7;    // d-tile
            float p0, p1;
            {
                union { unsigned u; _Float16 h[2]; } a;
                a.u = ld_agent_u32((const unsigned*)(ah_cur + abt * ARNN + 2 * tid));
                float a0 = (float)a.h[0], a1 = (float)a.h[1];
                float2 w0 = *(const float2*)(attWp + 2 * tid);
                float2 w1 = *(const float2*)(attWp + ARNN + 2 * tid);
                p0 = a0 * w0.x + a1 * w0.y;
                p1 = a0 * w1.x + a1 * w1.y;
            }
            #pragma unroll
            for (int off = 32; off > 0; off >>= 1) {
                p0 += __shfl_down(p0, off, 64);
                p1 += __shfl_down(p1, off, 64);
            }
            if (lane == 0) { wred8[wave][0] = p0; wred8[wave][1] = p1; }
            __syncthreads();
            if (tid == 0) {
                float q0 = attbp[0], q1 = attbp[1];
                #pragma unroll
                for (int w = 0; w < 8; ++w) { q0 += wred8[w][0]; q1 += wred8[w][1]; }
                float mn = ld_agent_f32(&mn_prv[abt]) + expf(q0) * 1.0f;  // MEAN_COEFF
                float sc = expf(q1) * 10.0f;                              // SCALE_COEFF
                if (dt == 0) {
                    st_agent_f32(&mn_cur[abt], mn);
                    st_agent_f32(&ps[(size_t)abt * Tsteps * 2 + (size_t)t * 2 + 0], q0);
                    st_agent_f32(&ps[(size_t)abt * Tsteps * 2 + (size_t)t * 2 + 1], q1);
                }
                bc2[0] = mn; bc2[1] = sc;
            }
            __syncthreads();
            const float mn = bc2[0], sc = bc2[1];
            const float inv_s = 1.f / sc;
            const float coef = 0.3989422804014327f * inv_s;
            const int len = mlen[abt];
            {
                float z = ((float)tid - mn) * inv_s;
                float wv = (tid < len) ? expf(-0.5f * z * z) * coef : 0.f;
                wsh[tid] = wv;
                if (dt == 0)
                    st_agent_f32(&aligns[(size_t)abt * Tsteps * Lmem + (size_t)t * Lmem + tid], wv);
            }
            __syncthreads();
            // ctx over +-9 sigma window: thread = (d-octet = wave, row = lane)
            int lo = (int)fmaxf(0.f, floorf(mn - 9.f * sc));
            int hi = (int)fminf((float)len, ceilf(mn + 9.f * sc) + 1.f);
            const int d8 = (dt << 6) + (wave << 3);
            const half_t* mb = mem16 + (size_t)abt * Lmem * ENCD + d8;
            float acc[8] = {0.f,0.f,0.f,0.f,0.f,0.f,0.f,0.f};
            for (int l = lo + lane; l < hi; l += 64) {
                f16x8 mv = *(const f16x8*)(mb + (size_t)l * ENCD);   // plain, L2-hot
                float w = wsh[l];
                #pragma unroll
                for (int j = 0; j < 8; ++j) acc[j] += w * (float)mv[j];
            }
            #pragma unroll
            for (int off = 32; off > 0; off >>= 1) {
                #pragma unroll
                for (int j = 0; j < 8; ++j) acc[j] += __shfl_down(acc[j], off, 64);
            }
            if (lane == 0) {
                #pragma unroll
                for (int j = 0; j < 4; ++j) {
                    union { unsigned u; _Float16 h[2]; } pk;
                    pk.h[0] = (_Float16)acc[2 * j];
                    pk.h[1] = (_Float16)acc[2 * j + 1];
                    __hip_atomic_store((unsigned*)(ctx_cur + abt * ENCD + d8 + 2 * j), pk.u,
                                       __ATOMIC_RELAXED, __HIP_MEMORY_SCOPE_AGENT);
                }
            }
        }
        if (t > 0) {
            // outproj for step t-1: row n = blk; two 6-chunk batches
            const int b_o = tid & 31;
            const int ks  = tid >> 5;
            const half_t* wrow = Wo + (size_t)blk * (DRNN + ENCD) + ks * 96;
            float outacc = 0.f;
            #pragma unroll
            for (int half = 0; half < 2; ++half) {
                f16x8 wv[6], av[6];
                #pragma unroll
                for (int c8 = 0; c8 < 6; ++c8) {
                    const int cc = half * 6 + c8;
                    const int k = ks * 96 + cc * 8;
                    wv[c8] = *(const f16x8*)(wrow + cc * 8);   // plain, L2-hot
                    const half_t* ap = (k < DRNN) ? (dh_s + b_o * DRNN + k)
                                                  : (ctx_prv + b_o * ENCD + (k - DRNN));
                    av[c8] = ld_agent_f16x8(ap);
                }
                #pragma unroll
                for (int c8 = 0; c8 < 6; ++c8)
                    #pragma unroll
                    for (int e = 0; e < 8; ++e)
                        outacc += (float)wv[c8][e] * (float)av[c8][e];
            }
            lred[ks][b_o] = outacc;
            __syncthreads();
            if (tid < 32) {
                float s = 0.f;
                #pragma unroll
                for (int q = 0; q < 16; ++q) s += lred[q][tid];
                st_agent_f32(&logits[(size_t)tid * Tsteps * NSYM + (size_t)(t - 1) * NSYM + blk],
                             s + ob[blk]);
            }
        }
        if (t < Tsteps) {
            ++ph; g_arrive(flags, ph);
            // ---- cross-barrier prefetch for next iteration's phase1 ----
            if (t + 1 < Tsteps) {
                const half_t* s0n = xpre + (size_t)(t + 1) * Bsz * PRE;
                #pragma unroll
                for (int i = 0; i < NMA; ++i) {
                    const int kg = kq * KAQ + i * 32 + (kh << 3);
                    if (kg < PRE)
                        bvA[i] = *(const f16x8*)(s0n + bb * PRE + kg);
                    else if (kg >= PRE + ENCD)
                        bvA[i] = ld_agent_f16x8(ah_cur + bb * ARNN + (kg - PRE - ENCD));
                }
            }
            #pragma unroll
            for (int i = 0; i < NMD; ++i) {
                const int kg = kq * KDQ + i * 32 + (kh << 3);
                if (kg < ARNN)
                    bvD[i] = ld_agent_f16x8(ah_cur + bb * ARNN + kg);
                else if (kg >= ARNN + ENCD)
                    bvD[i] = ld_agent_f16x8(dh_s + bb * DRNN + (kg - ARNN - ENCD));
            }
            #pragma unroll
            for (int i = 0; i < NMA; ++i) keep16(bvA[i]);
            #pragma unroll
            for (int i = 0; i < NMD; ++i) keep16(bvD[i]);
            g_wait(flags, ph);
            // ---- post-wait: ctx_t segments (the only ph2-produced data) ----
            if (t + 1 < Tsteps) {
                #pragma unroll
                for (int i = 0; i < NMA; ++i) {
                    const int kg = kq * KAQ + i * 32 + (kh << 3);
                    if (kg >= PRE && kg < PRE + ENCD)
                        bvA[i] = ld_agent_f16x8(ctx_cur + bb * ENCD + (kg - PRE));
                }
            }
            #pragma unroll
            for (int i = 0; i < NMD; ++i) {
                const int kg = kq * KDQ + i * 32 + (kh << 3);
                if (kg >= ARNN && kg < ARNN + ENCD)
                    bvD[i] = ld_agent_f16x8(ctx_cur + bb * ENCD + (kg - ARNN));
            }
        }
    }
}

// ---------------------------------------------------------------------------
extern "C" void kernel_launch(void* const* d_in, const int* in_sizes, int n_in,
                              void* d_out, int out_size, void* d_ws, size_t ws_size,
                              hipStream_t stream)
{
    (void)in_sizes; (void)n_in; (void)out_size; (void)ws_size;
    const float* memory = (const float*)d_in[0];
    const float* din    = (const float*)d_in[1];
    const int*   mlen   = (const int*)d_in[2];
    const float* pW1    = (const float*)d_in[3];
    const float* pb1    = (const float*)d_in[4];
    const float* pW2    = (const float*)d_in[5];
    const float* pb2    = (const float*)d_in[6];
    const float* aWih   = (const float*)d_in[7];
    const float* aWhh   = (const float*)d_in[8];
    const float* abih   = (const float*)d_in[9];
    const float* abhh   = (const float*)d_in[10];
    const float* attWp  = (const float*)d_in[11];
    const float* attbp  = (const float*)d_in[12];
    const float* dWih   = (const float*)d_in[13];
    const float* dWhh   = (const float*)d_in[14];
    const float* dbih   = (const float*)d_in[15];
    const float* dbhh   = (const float*)d_in[16];
    const float* oW     = (const float*)d_in[17];
    const float* ob     = (const float*)d_in[18];

    float* logits = (float*)d_out;
    float* aligns = logits + (size_t)Bsz * Tsteps * NSYM;
    float* ps     = aligns + (size_t)Bsz * Tsteps * Lmem;

    char* base = (char*)d_ws;
    auto alloc = [&](size_t bytes) -> char* {
        char* p = base; base += (bytes + 255) & ~(size_t)255; return p;
    };
    half_t* Wcat_a = (half_t*)alloc((size_t)4096 * KA * 2);
    half_t* Wcat_d = (half_t*)alloc((size_t)4096 * KD * 2);
    half_t* Wo     = (half_t*)alloc((size_t)NSYM * (DRNN + ENCD) * 2);
    float*  bsum_a = (float*)alloc(4096 * 4);
    float*  bsum_d = (float*)alloc(4096 * 4);
    half_t* xpre   = (half_t*)alloc((size_t)Tsteps * Bsz * PRE * 2);
    half_t* mem16  = (half_t*)alloc((size_t)Bsz * Lmem * ENCD * 2);
    half_t* ah0    = (half_t*)alloc(Bsz * ARNN * 2);
    half_t* ah1    = (half_t*)alloc(Bsz * ARNN * 2);
    half_t* dh0    = (half_t*)alloc(Bsz * DRNN * 2);
    half_t* dh1    = (half_t*)alloc(Bsz * DRNN * 2);
    half_t* ctx0   = (half_t*)alloc(Bsz * ENCD * 2);
    half_t* ctx1   = (half_t*)alloc(Bsz * ENCD * 2);
    float*  mean0  = (float*)alloc(Bsz * 4);
    float*  mean1  = (float*)alloc(Bsz * 4);
    unsigned* flags = (unsigned*)alloc(256 * 16 * 4);

    (void)hipMemsetAsync(ah1,   0, Bsz * ARNN * 2, stream);
    (void)hipMemsetAsync(dh1,   0, Bsz * DRNN * 2, stream);
    (void)hipMemsetAsync(ctx1,  0, Bsz * ENCD * 2, stream);
    (void)hipMemsetAsync(mean0, 0, Bsz * 4, stream);
    (void)hipMemsetAsync(mean1, 0, Bsz * 4, stream);
    (void)hipMemsetAsync(flags, 0, 256 * 16 * 4, stream);

    conv_lstm_w<PRE + ENCD, ARNN><<<4096, 256, 0, stream>>>(
        aWih, aWhh, abih, abhh, Wcat_a, bsum_a);
    conv_lstm_w<ARNN + ENCD, DRNN><<<4096, 256, 0, stream>>>(
        dWih, dWhh, dbih, dbhh, Wcat_d, bsum_d);
    conv_mat<<<768, 256, 0, stream>>>(oW, Wo, NSYM * (DRNN + ENCD));
    conv_mat<<<4096, 256, 0, stream>>>(memory, mem16, Bsz * Lmem * ENCD);
    prenet_kernel<<<Tsteps * Bsz / 8, 256, 0, stream>>>(din, pW1, pb1, pW2, pb2, xpre);

    decoder_persistent<<<256, 512, 0, stream>>>(
        Wcat_a, bsum_a, Wcat_d, bsum_d, Wo, ob, xpre,
        attWp, attbp, mlen, mem16,
        ah0, ah1, dh0, dh1, ctx0, ctx1, mean0, mean1,
        logits, aligns, ps,
        flags);
}